// Round 1
// baseline (4792.580 us; speedup 1.0000x reference)
//
#include <hip/hip_runtime.h>

typedef __attribute__((ext_vector_type(8))) short short8;
typedef __attribute__((ext_vector_type(4))) float floatx4;

#define T_STEPS 1024
#define BATCH   256
#define INSZ    128
#define HID     512
#define OUTSZ   32

#define MFMA16(a,b,c) __builtin_amdgcn_mfma_f32_16x16x32_bf16((a),(b),(c),0,0,0)

// bf16 helpers (RNE)
static __device__ __forceinline__ short f2bf(float f) {
  unsigned int u = __float_as_uint(f);
  u += 0x7fffu + ((u >> 16) & 1u);
  return (short)(u >> 16);
}
static __device__ __forceinline__ float bf2f(short s) {
  return __uint_as_float(((unsigned int)(unsigned short)s) << 16);
}
// packed f32->bf16 (RNE), 1 inst for 2 values
static __device__ __forceinline__ unsigned cvt_pk_bf16(float lo, float hi) {
  unsigned r;
  asm("v_cvt_pk_bf16_f32 %0, %1, %2" : "=v"(r) : "v"(lo), "v"(hi));
  return r;
}

// ---------------------------------------------------------------------------
// Pack weights into MFMA B-fragment-linear bf16 layouts.
// B-frag for 16x16x32: lane = ((k%32)/8)*16 + (n%16), elem j = k%8.
// frag id = kt*NT + nt ; pos = (frag*64 + lane)*8 + j
// ---------------------------------------------------------------------------
__global__ __launch_bounds__(256) void pack_kernel(
    const float* __restrict__ W_rec, const float* __restrict__ W_in,
    const float* __restrict__ W_out,
    short* __restrict__ w_rec_p, short* __restrict__ w_in_p,
    short* __restrict__ w_out_p) {
  int i = blockIdx.x * 256 + threadIdx.x;  // 0..262143
  {
    // W_rec[n][k] used as B[k][n]  (h @ W_rec^T)
    int n = i >> 9, k = i & 511;
    int pos = ((((k >> 5) * 32 + (n >> 4)) * 64 + ((k >> 3) & 3) * 16 + (n & 15)) << 3) + (k & 7);
    w_rec_p[pos] = f2bf(W_rec[i]);
  }
  if (i < INSZ * HID) {
    int k = i >> 9, n = i & 511;  // W_in[k][n] used as B[k][n]
    int pos = ((((k >> 5) * 32 + (n >> 4)) * 64 + ((k >> 3) & 3) * 16 + (n & 15)) << 3) + (k & 7);
    w_in_p[pos] = f2bf(W_in[i]);
  }
  if (i < HID * OUTSZ) {
    int k = i >> 5, o = i & 31;   // W_out[k][o] used as B[k][o], NT=2
    int pos = ((((k >> 5) * 2 + (o >> 4)) * 64 + ((k >> 3) & 3) * 16 + (o & 15)) << 3) + (k & 7);
    w_out_p[pos] = f2bf(W_out[i]);
  }
}

// ---------------------------------------------------------------------------
// Fused kernel, launched once per chunk phase c in [-1, nchunks]:
//   blocks [0,16)            : scan of chunk c          (if 0 <= c < nchunks)
//   blocks [16, 16+chunk)    : xproj of chunk c+1       (if c+1 < nchunks)
//   remaining chunk blocks   : out GEMM of chunk c-1    (if c-1 >= 0)
// xp / hs are double-buffered so all roles are independent within a launch.
// xp layout is C-fragment-linear bf16: elem ((t*16 + slab)*32 + ct)*64*4
//   + lane*4 + r   (ct = 16-col tile, r = acc reg) -> scan reads 8B/thread/ct.
// ---------------------------------------------------------------------------
__global__ __launch_bounds__(512, 2) void fused_kernel(
    const float* __restrict__ inputs,
    const short* __restrict__ w_rec_p, const short* __restrict__ w_in_p,
    const short* __restrict__ w_out_p,
    const float* __restrict__ b_rec, const float* __restrict__ b_out,
    short* __restrict__ xp0, short* __restrict__ xp1,
    short* __restrict__ hs0, short* __restrict__ hs1,
    float* __restrict__ h_carry, float* __restrict__ out,
    int c, int chunk, int nchunks) {
  __shared__ __align__(16) char smem[163840];  // union: scan 160K / out 8*16640
  const int tid  = threadIdx.x;
  const int wave = tid >> 6, lane = tid & 63;
  const int l15  = lane & 15, q = lane >> 4;

  const int sb = (c >= 0 && c < nchunks) ? 16 : 0;
  const int nx = (c + 1 < nchunks) ? chunk : 0;
  const int bid = blockIdx.x;

  if (bid < sb) {
    // ================= scan role: chunk c, 16 batch rows per block ==========
    short* w_lds = (short*)smem;               // 128 KB: W_rec ktiles 12..15
    short* hbuf  = (short*)(smem + 131072);    // 2 x 16KB double-buffered h
    const short* xp = (c & 1) ? xp1 : xp0;
    short* hs = (c & 1) ? hs1 : hs0;
    const int slab = bid * 16;
    const int first = (c == 0);

    // resident weight fragments, ktiles 0..11 (wave owns cols [wave*64,+64))
    short8 wreg[12][4];
    #pragma unroll
    for (int kt = 0; kt < 12; ++kt)
      #pragma unroll
      for (int nt = 0; nt < 4; ++nt)
        wreg[kt][nt] = *(const short8*)(w_rec_p + (((kt * 32 + wave * 4 + nt) * 64 + lane) << 3));

    // ktiles 12..15 -> LDS (frag-linear region contiguous in w_rec_p)
    for (int e = tid * 8; e < 4 * 32 * 512; e += 512 * 8)
      *(short8*)(w_lds + e) = *(const short8*)(w_rec_p + 12 * 32 * 512 + e);

    // carried state -> fp32 regs + swizzled bf16 LDS (buffer 0)
    float hold[4][4];
    #pragma unroll
    for (int nt = 0; nt < 4; ++nt) {
      int col = wave * 64 + nt * 16 + l15;
      int ck = col >> 3, cl = col & 7;
      #pragma unroll
      for (int r = 0; r < 4; ++r) {
        int row = q * 4 + r;
        float v = 0.f;
        if (!first) v = h_carry[(size_t)(slab + row) * HID + col];
        hold[nt][r] = v;
        hbuf[row * 512 + ((ck ^ row) << 3) + cl] = f2bf(v);
      }
    }

    // prefetch xp for t=0 into registers (4 x 8B, coalesced)
    uint2 xv[4];
    #pragma unroll
    for (int nt = 0; nt < 4; ++nt)
      xv[nt] = *(const uint2*)(xp + ((((size_t)0 * 16 + bid) * 32 + wave * 4 + nt) * 64 + lane) * 4);

    const float alpha = (float)(0.1 / 100.0);
    const float onem  = (float)(1.0 - 0.1 / 100.0);

    __syncthreads();

    int p = 0;
    for (int t = 0; t < chunk; ++t) {
      const short* hb = hbuf + p * (16 * 512);        // state h_{t}
      short* hnb = hbuf + (p ^ 1) * (16 * 512);       // will hold h_{t+1}

      // acc init = xp[t] (C-in of MFMA) -- replaces LDS xp staging + add
      floatx4 acc[4];
      #pragma unroll
      for (int nt = 0; nt < 4; ++nt) {
        acc[nt][0] = bf2f((short)(xv[nt].x & 0xffffu));
        acc[nt][1] = bf2f((short)(xv[nt].x >> 16));
        acc[nt][2] = bf2f((short)(xv[nt].y & 0xffffu));
        acc[nt][3] = bf2f((short)(xv[nt].y >> 16));
      }
      // prefetch xp[t+1]; retires long before the barrier
      if (t + 1 < chunk) {
        #pragma unroll
        for (int nt = 0; nt < 4; ++nt)
          xv[nt] = *(const uint2*)(xp + ((((size_t)(t + 1) * 16 + bid) * 32 + wave * 4 + nt) * 64 + lane) * 4);
      }

      // store hs[t-1] from stable buffer hb (reads-only overlap with MFMA)
      if (t > 0) {
        int e = tid * 16;
        int row = e >> 9, c0 = (e & 511) >> 3;
        short8 v0 = *(const short8*)(hb + row * 512 + (((c0    ) ^ row) << 3));
        short8 v1 = *(const short8*)(hb + row * 512 + (((c0 + 1) ^ row) << 3));
        short* dst = hs + ((size_t)(t - 1) * BATCH + slab) * HID + e;
        *(short8*)(dst) = v0;
        *(short8*)(dst + 8) = v1;
      }

      // MFMA: h_t @ W_rec^T, ktiles 0..11 from regs, 12..15 from LDS
      #pragma unroll
      for (int kt = 0; kt < 12; ++kt) {
        short8 afr = *(const short8*)(hb + l15 * 512 + (((kt * 4 + q) ^ l15) << 3));
        #pragma unroll
        for (int nt = 0; nt < 4; ++nt)
          acc[nt] = MFMA16(afr, wreg[kt][nt], acc[nt]);
      }
      #pragma unroll
      for (int kt = 12; kt < 16; ++kt) {
        short8 afr = *(const short8*)(hb + l15 * 512 + (((kt * 4 + q) ^ l15) << 3));
        #pragma unroll
        for (int nt = 0; nt < 4; ++nt) {
          short8 bfr = *(const short8*)(w_lds + (((kt - 12) * 32 + wave * 4 + nt) << 9) + lane * 8);
          acc[nt] = MFMA16(afr, bfr, acc[nt]);
        }
      }

      // epilogue: CTRNN update in fp32 regs, write bf16 h_{t+1} to other buf
      #pragma unroll
      for (int nt = 0; nt < 4; ++nt) {
        int col = wave * 64 + nt * 16 + l15;
        int ck = col >> 3, cl = col & 7;
        float h0 = onem * hold[nt][0] + alpha * fmaxf(acc[nt][0], 0.f);
        float h1 = onem * hold[nt][1] + alpha * fmaxf(acc[nt][1], 0.f);
        float h2 = onem * hold[nt][2] + alpha * fmaxf(acc[nt][2], 0.f);
        float h3 = onem * hold[nt][3] + alpha * fmaxf(acc[nt][3], 0.f);
        hold[nt][0] = h0; hold[nt][1] = h1; hold[nt][2] = h2; hold[nt][3] = h3;
        unsigned u01 = cvt_pk_bf16(h0, h1);
        unsigned u23 = cvt_pk_bf16(h2, h3);
        int r0 = q * 4;
        hnb[(r0 + 0) * 512 + ((ck ^ (r0 + 0)) << 3) + cl] = (short)(u01 & 0xffffu);
        hnb[(r0 + 1) * 512 + ((ck ^ (r0 + 1)) << 3) + cl] = (short)(u01 >> 16);
        hnb[(r0 + 2) * 512 + ((ck ^ (r0 + 2)) << 3) + cl] = (short)(u23 & 0xffffu);
        hnb[(r0 + 3) * 512 + ((ck ^ (r0 + 3)) << 3) + cl] = (short)(u23 >> 16);
      }
      __syncthreads();  // single barrier per step (WAR safe: write buf != read buf)
      p ^= 1;
    }

    // tail: hs[chunk-1] + fp32 carry
    {
      const short* hb = hbuf + p * (16 * 512);
      int e = tid * 16;
      int row = e >> 9, c0 = (e & 511) >> 3;
      short8 v0 = *(const short8*)(hb + row * 512 + (((c0    ) ^ row) << 3));
      short8 v1 = *(const short8*)(hb + row * 512 + (((c0 + 1) ^ row) << 3));
      short* dst = hs + ((size_t)(chunk - 1) * BATCH + slab) * HID + e;
      *(short8*)(dst) = v0;
      *(short8*)(dst + 8) = v1;
    }
    #pragma unroll
    for (int nt = 0; nt < 4; ++nt) {
      int col = wave * 64 + nt * 16 + l15;
      #pragma unroll
      for (int r = 0; r < 4; ++r)
        h_carry[(size_t)(slab + q * 4 + r) * HID + col] = hold[nt][r];
    }

  } else if (bid - sb < nx) {
    // ================= xproj role: one timestep of chunk c+1 ================
    const int tt = bid - sb;
    const int cc = c + 1;
    short* xpw = (cc & 1) ? xp1 : xp0;
    const int t_abs = cc * chunk + tt;

    short8 bfr[4][4];  // ct = wave*4+i, kt 0..3
    #pragma unroll
    for (int i = 0; i < 4; ++i)
      #pragma unroll
      for (int kt = 0; kt < 4; ++kt)
        bfr[i][kt] = *(const short8*)(w_in_p + (((kt * 32 + wave * 4 + i) * 64 + lane) << 3));
    float brv[4];
    #pragma unroll
    for (int i = 0; i < 4; ++i) brv[i] = b_rec[(wave * 4 + i) * 16 + l15];

    for (int it = 0; it < 16; ++it) {
      const float* arow = inputs + ((size_t)t_abs * BATCH + it * 16 + l15) * INSZ + q * 8;
      short8 afr[4];
      #pragma unroll
      for (int kt = 0; kt < 4; ++kt) {
        short8 s;
        #pragma unroll
        for (int j = 0; j < 4; ++j) {
          unsigned u = cvt_pk_bf16(arow[kt * 32 + 2 * j], arow[kt * 32 + 2 * j + 1]);
          s[2 * j] = (short)(u & 0xffffu);
          s[2 * j + 1] = (short)(u >> 16);
        }
        afr[kt] = s;
      }
      floatx4 acc[4];
      #pragma unroll
      for (int i = 0; i < 4; ++i) acc[i] = (floatx4){0.f, 0.f, 0.f, 0.f};
      #pragma unroll
      for (int kt = 0; kt < 4; ++kt)
        #pragma unroll
        for (int i = 0; i < 4; ++i)
          acc[i] = MFMA16(afr[kt], bfr[i][kt], acc[i]);
      // store (acc + b_rec) as bf16 in fragment-linear layout: 8B/thread/ct
      #pragma unroll
      for (int i = 0; i < 4; ++i) {
        unsigned u01 = cvt_pk_bf16(acc[i][0] + brv[i], acc[i][1] + brv[i]);
        unsigned u23 = cvt_pk_bf16(acc[i][2] + brv[i], acc[i][3] + brv[i]);
        uint2 u; u.x = u01; u.y = u23;
        *(uint2*)(xpw + ((((size_t)tt * 16 + it) * 32 + wave * 4 + i) * 64 + lane) * 4) = u;
      }
    }

  } else {
    // ================= out role: one timestep of chunk c-1 ==================
    const int tt = bid - sb - nx;
    const int cc = c - 1;
    const short* hsr = (cc & 1) ? hs1 : hs0;
    short* al = (short*)smem + wave * (16 * 520);  // wave-private padded tile

    short8 bfr[16][2];
    #pragma unroll
    for (int kt = 0; kt < 16; ++kt)
      #pragma unroll
      for (int ot = 0; ot < 2; ++ot)
        bfr[kt][ot] = *(const short8*)(w_out_p + (((kt * 2 + ot) * 64 + lane) << 3));
    float bov[2] = { b_out[l15], b_out[16 + l15] };

    #pragma unroll
    for (int itm = 0; itm < 2; ++itm) {
      int mt = wave * 2 + itm;  // 16-row group within the timestep
      const short* src = hsr + ((size_t)tt * BATCH + mt * 16) * HID;
      #pragma unroll
      for (int r = 0; r < 16; ++r)
        *(short8*)(al + r * 520 + lane * 8) = *(const short8*)(src + r * 512 + lane * 8);
      // wave-private tile: in-wave DS ordering suffices, no barrier

      floatx4 acc2[2];
      acc2[0] = (floatx4){0.f, 0.f, 0.f, 0.f};
      acc2[1] = (floatx4){0.f, 0.f, 0.f, 0.f};
      #pragma unroll
      for (int kt = 0; kt < 16; ++kt) {
        short8 afr = *(const short8*)(al + l15 * 520 + kt * 32 + q * 8);
        acc2[0] = MFMA16(afr, bfr[kt][0], acc2[0]);
        acc2[1] = MFMA16(afr, bfr[kt][1], acc2[1]);
      }
      float* outp = out + ((size_t)(cc * chunk + tt) * BATCH + mt * 16) * OUTSZ;
      #pragma unroll
      for (int ot = 0; ot < 2; ++ot)
        #pragma unroll
        for (int r = 0; r < 4; ++r)
          outp[(size_t)(q * 4 + r) * OUTSZ + ot * 16 + l15] = acc2[ot][r] + bov[ot];
    }
  }
}

// ---------------------------------------------------------------------------
extern "C" void kernel_launch(void* const* d_in, const int* in_sizes, int n_in,
                              void* d_out, int out_size, void* d_ws, size_t ws_size,
                              hipStream_t stream) {
  const float* inputs = (const float*)d_in[0];  // [1024,256,128]
  const float* W_rec  = (const float*)d_in[1];  // [512,512]
  const float* W_in   = (const float*)d_in[2];  // [128,512]
  const float* b_rec  = (const float*)d_in[3];  // [512]
  const float* W_out  = (const float*)d_in[4];  // [512,32]
  const float* b_out  = (const float*)d_in[5];  // [32]
  float* out = (float*)d_out;                   // [1024,256,32]

  char* ws = (char*)d_ws;
  // fixed region (< 2 MB): packed weights + fp32 h carry
  short* w_rec_p = (short*)(ws);                       // 512 KB
  short* w_in_p  = (short*)(ws + 524288);              // 128 KB
  short* w_out_p = (short*)(ws + 655360);              //  32 KB
  float* h_carry = (float*)(ws + 688128);              // 512 KB
  const size_t fixed_end = 2u << 20;                   // 2 MB

  // double-buffered xp + hs: 4 buffers of chunk*256KB each -> 1 MB per step
  const size_t per_step = (size_t)BATCH * HID * 2 * 4;
  int chunk = T_STEPS;
  while (chunk > 1 && fixed_end + (size_t)chunk * per_step > ws_size) chunk >>= 1;
  if (fixed_end + (size_t)chunk * per_step > ws_size) return;  // ws too small
  const int nchunks = T_STEPS / chunk;

  const size_t buf = (size_t)chunk * BATCH * HID * 2;  // bytes per buffer
  short* xp0 = (short*)(ws + fixed_end);
  short* xp1 = (short*)(ws + fixed_end + buf);
  short* hs0 = (short*)(ws + fixed_end + 2 * buf);
  short* hs1 = (short*)(ws + fixed_end + 3 * buf);

  pack_kernel<<<1024, 256, 0, stream>>>(W_rec, W_in, W_out, w_rec_p, w_in_p, w_out_p);

  for (int c = -1; c <= nchunks; ++c) {
    int sb = (c >= 0 && c < nchunks) ? 16 : 0;
    int nx = (c + 1 >= 0 && c + 1 < nchunks) ? chunk : 0;
    int no = (c - 1 >= 0 && c - 1 < nchunks) ? chunk : 0;
    int grid = sb + nx + no;
    if (!grid) continue;
    fused_kernel<<<grid, 512, 0, stream>>>(inputs, w_rec_p, w_in_p, w_out_p,
        b_rec, b_out, xp0, xp1, hs0, hs1, h_carry, out, c, chunk, nchunks);
  }
}

// Round 2
// 4769.741 us; speedup vs baseline: 1.0048x; 1.0048x over previous
//
#include <hip/hip_runtime.h>

typedef __attribute__((ext_vector_type(8))) short short8;
typedef __attribute__((ext_vector_type(4))) float floatx4;

#define T_STEPS 1024
#define BATCH   256
#define INSZ    128
#define HID     512
#define OUTSZ   32

#define MFMA16(a,b,c) __builtin_amdgcn_mfma_f32_16x16x32_bf16((a),(b),(c),0,0,0)

// bf16 helpers (RNE)
static __device__ __forceinline__ short f2bf(float f) {
  unsigned int u = __float_as_uint(f);
  u += 0x7fffu + ((u >> 16) & 1u);
  return (short)(u >> 16);
}
static __device__ __forceinline__ float bf2f(short s) {
  return __uint_as_float(((unsigned int)(unsigned short)s) << 16);
}
// packed f32->bf16 (RNE), 1 inst for 2 values
static __device__ __forceinline__ unsigned cvt_pk_bf16(float lo, float hi) {
  unsigned r;
  asm("v_cvt_pk_bf16_f32 %0, %1, %2" : "=v"(r) : "v"(lo), "v"(hi));
  return r;
}

// ---------------------------------------------------------------------------
// Pack weights into MFMA B-fragment-linear bf16 layouts.
// B-frag for 16x16x32: lane = ((k%32)/8)*16 + (n%16), elem j = k%8.
// frag id = kt*NT + nt ; pos = (frag*64 + lane)*8 + j
// ---------------------------------------------------------------------------
__global__ __launch_bounds__(256) void pack_kernel(
    const float* __restrict__ W_rec, const float* __restrict__ W_in,
    const float* __restrict__ W_out,
    short* __restrict__ w_rec_p, short* __restrict__ w_in_p,
    short* __restrict__ w_out_p) {
  int i = blockIdx.x * 256 + threadIdx.x;  // 0..262143
  {
    // W_rec[n][k] used as B[k][n]  (h @ W_rec^T)
    int n = i >> 9, k = i & 511;
    int pos = ((((k >> 5) * 32 + (n >> 4)) * 64 + ((k >> 3) & 3) * 16 + (n & 15)) << 3) + (k & 7);
    w_rec_p[pos] = f2bf(W_rec[i]);
  }
  if (i < INSZ * HID) {
    int k = i >> 9, n = i & 511;  // W_in[k][n] used as B[k][n]
    int pos = ((((k >> 5) * 32 + (n >> 4)) * 64 + ((k >> 3) & 3) * 16 + (n & 15)) << 3) + (k & 7);
    w_in_p[pos] = f2bf(W_in[i]);
  }
  if (i < HID * OUTSZ) {
    int k = i >> 5, o = i & 31;   // W_out[k][o] used as B[k][o], NT=2
    int pos = ((((k >> 5) * 2 + (o >> 4)) * 64 + ((k >> 3) & 3) * 16 + (o & 15)) << 3) + (k & 7);
    w_out_p[pos] = f2bf(W_out[i]);
  }
}

// ---------------------------------------------------------------------------
// Fused kernel, launched once per chunk phase c in [-1, nchunks]:
//   blocks [0,16)            : scan of chunk c          (if 0 <= c < nchunks)
//   blocks [16, 16+chunk)    : xproj of chunk c+1       (if c+1 < nchunks)
//   remaining chunk blocks   : out GEMM of chunk c-1    (if c-1 >= 0)
// xp / hs are double-buffered so all roles are independent within a launch.
//
// __launch_bounds__(512, 1): LDS=160KB already forces 1 block/CU (8 waves,
// 2/SIMD) -> HW register cap is 256/wave. The previous (512,2) capped the
// allocator at 128 VGPRs, forcing the 192-reg wreg[] tile to spill and be
// re-fetched every timestep (~384KB/CU/step through L1 fill) -- that was the
// scan bottleneck. With 256 regs, W_rec ktiles 0..11 are truly resident.
// ---------------------------------------------------------------------------
__global__ __launch_bounds__(512, 1) void fused_kernel(
    const float* __restrict__ inputs,
    const short* __restrict__ w_rec_p, const short* __restrict__ w_in_p,
    const short* __restrict__ w_out_p,
    const float* __restrict__ b_rec, const float* __restrict__ b_out,
    short* __restrict__ xp0, short* __restrict__ xp1,
    short* __restrict__ hs0, short* __restrict__ hs1,
    float* __restrict__ h_carry, float* __restrict__ out,
    int c, int chunk, int nchunks) {
  __shared__ __align__(16) char smem[163840];  // union: scan 160K / out 8*16640
  const int tid  = threadIdx.x;
  const int wave = tid >> 6, lane = tid & 63;
  const int l15  = lane & 15, q = lane >> 4;

  const int sb = (c >= 0 && c < nchunks) ? 16 : 0;
  const int nx = (c + 1 < nchunks) ? chunk : 0;
  const int bid = blockIdx.x;

  if (bid < sb) {
    // ================= scan role: chunk c, 16 batch rows per block ==========
    short* w_lds = (short*)smem;               // 128 KB: W_rec ktiles 12..15
    short* hbuf  = (short*)(smem + 131072);    // 2 x 16KB double-buffered h
    const short* xp = (c & 1) ? xp1 : xp0;
    short* hs = (c & 1) ? hs1 : hs0;
    const int slab = bid * 16;
    const int first = (c == 0);

    // resident weight fragments, ktiles 0..11 (wave owns cols [wave*64,+64))
    short8 wreg[12][4];
    #pragma unroll
    for (int kt = 0; kt < 12; ++kt)
      #pragma unroll
      for (int nt = 0; nt < 4; ++nt)
        wreg[kt][nt] = *(const short8*)(w_rec_p + (((kt * 32 + wave * 4 + nt) * 64 + lane) << 3));

    // ktiles 12..15 -> LDS (frag-linear region contiguous in w_rec_p)
    for (int e = tid * 8; e < 4 * 32 * 512; e += 512 * 8)
      *(short8*)(w_lds + e) = *(const short8*)(w_rec_p + 12 * 32 * 512 + e);

    // carried state -> fp32 regs + swizzled bf16 LDS (buffer 0)
    float hold[4][4];
    #pragma unroll
    for (int nt = 0; nt < 4; ++nt) {
      int col = wave * 64 + nt * 16 + l15;
      int ck = col >> 3, cl = col & 7;
      #pragma unroll
      for (int r = 0; r < 4; ++r) {
        int row = q * 4 + r;
        float v = 0.f;
        if (!first) v = h_carry[(size_t)(slab + row) * HID + col];
        hold[nt][r] = v;
        hbuf[row * 512 + ((ck ^ row) << 3) + cl] = f2bf(v);
      }
    }

    // prefetch xp for t=0 into registers (4 x 8B, coalesced)
    uint2 xv[4];
    #pragma unroll
    for (int nt = 0; nt < 4; ++nt)
      xv[nt] = *(const uint2*)(xp + ((((size_t)0 * 16 + bid) * 32 + wave * 4 + nt) * 64 + lane) * 4);

    const float alpha = (float)(0.1 / 100.0);
    const float onem  = (float)(1.0 - 0.1 / 100.0);

    __syncthreads();

    int p = 0;
    for (int t = 0; t < chunk; ++t) {
      const short* hb = hbuf + p * (16 * 512);        // state h_{t}
      short* hnb = hbuf + (p ^ 1) * (16 * 512);       // will hold h_{t+1}

      // acc init = xp[t] (C-in of MFMA) -- replaces LDS xp staging + add
      floatx4 acc[4];
      #pragma unroll
      for (int nt = 0; nt < 4; ++nt) {
        acc[nt][0] = bf2f((short)(xv[nt].x & 0xffffu));
        acc[nt][1] = bf2f((short)(xv[nt].x >> 16));
        acc[nt][2] = bf2f((short)(xv[nt].y & 0xffffu));
        acc[nt][3] = bf2f((short)(xv[nt].y >> 16));
      }
      // prefetch xp[t+1]; retires long before the barrier
      if (t + 1 < chunk) {
        #pragma unroll
        for (int nt = 0; nt < 4; ++nt)
          xv[nt] = *(const uint2*)(xp + ((((size_t)(t + 1) * 16 + bid) * 32 + wave * 4 + nt) * 64 + lane) * 4);
      }

      // store hs[t-1] from stable buffer hb (reads-only overlap with MFMA)
      if (t > 0) {
        int e = tid * 16;
        int row = e >> 9, c0 = (e & 511) >> 3;
        short8 v0 = *(const short8*)(hb + row * 512 + (((c0    ) ^ row) << 3));
        short8 v1 = *(const short8*)(hb + row * 512 + (((c0 + 1) ^ row) << 3));
        short* dst = hs + ((size_t)(t - 1) * BATCH + slab) * HID + e;
        *(short8*)(dst) = v0;
        *(short8*)(dst + 8) = v1;
      }

      // MFMA: h_t @ W_rec^T, ktiles 0..11 from regs, 12..15 from LDS
      #pragma unroll
      for (int kt = 0; kt < 12; ++kt) {
        short8 afr = *(const short8*)(hb + l15 * 512 + (((kt * 4 + q) ^ l15) << 3));
        #pragma unroll
        for (int nt = 0; nt < 4; ++nt)
          acc[nt] = MFMA16(afr, wreg[kt][nt], acc[nt]);
      }
      #pragma unroll
      for (int kt = 12; kt < 16; ++kt) {
        short8 afr = *(const short8*)(hb + l15 * 512 + (((kt * 4 + q) ^ l15) << 3));
        #pragma unroll
        for (int nt = 0; nt < 4; ++nt) {
          short8 bfr = *(const short8*)(w_lds + (((kt - 12) * 32 + wave * 4 + nt) << 9) + lane * 8);
          acc[nt] = MFMA16(afr, bfr, acc[nt]);
        }
      }

      // epilogue: CTRNN update in fp32 regs, write bf16 h_{t+1} to other buf
      #pragma unroll
      for (int nt = 0; nt < 4; ++nt) {
        int col = wave * 64 + nt * 16 + l15;
        int ck = col >> 3, cl = col & 7;
        float h0 = onem * hold[nt][0] + alpha * fmaxf(acc[nt][0], 0.f);
        float h1 = onem * hold[nt][1] + alpha * fmaxf(acc[nt][1], 0.f);
        float h2 = onem * hold[nt][2] + alpha * fmaxf(acc[nt][2], 0.f);
        float h3 = onem * hold[nt][3] + alpha * fmaxf(acc[nt][3], 0.f);
        hold[nt][0] = h0; hold[nt][1] = h1; hold[nt][2] = h2; hold[nt][3] = h3;
        unsigned u01 = cvt_pk_bf16(h0, h1);
        unsigned u23 = cvt_pk_bf16(h2, h3);
        int r0 = q * 4;
        hnb[(r0 + 0) * 512 + ((ck ^ (r0 + 0)) << 3) + cl] = (short)(u01 & 0xffffu);
        hnb[(r0 + 1) * 512 + ((ck ^ (r0 + 1)) << 3) + cl] = (short)(u01 >> 16);
        hnb[(r0 + 2) * 512 + ((ck ^ (r0 + 2)) << 3) + cl] = (short)(u23 & 0xffffu);
        hnb[(r0 + 3) * 512 + ((ck ^ (r0 + 3)) << 3) + cl] = (short)(u23 >> 16);
      }
      __syncthreads();  // single barrier per step (WAR safe: write buf != read buf)
      p ^= 1;
    }

    // tail: hs[chunk-1] + fp32 carry
    {
      const short* hb = hbuf + p * (16 * 512);
      int e = tid * 16;
      int row = e >> 9, c0 = (e & 511) >> 3;
      short8 v0 = *(const short8*)(hb + row * 512 + (((c0    ) ^ row) << 3));
      short8 v1 = *(const short8*)(hb + row * 512 + (((c0 + 1) ^ row) << 3));
      short* dst = hs + ((size_t)(chunk - 1) * BATCH + slab) * HID + e;
      *(short8*)(dst) = v0;
      *(short8*)(dst + 8) = v1;
    }
    #pragma unroll
    for (int nt = 0; nt < 4; ++nt) {
      int col = wave * 64 + nt * 16 + l15;
      #pragma unroll
      for (int r = 0; r < 4; ++r)
        h_carry[(size_t)(slab + q * 4 + r) * HID + col] = hold[nt][r];
    }

  } else if (bid - sb < nx) {
    // ================= xproj role: one timestep of chunk c+1 ================
    const int tt = bid - sb;
    const int cc = c + 1;
    short* xpw = (cc & 1) ? xp1 : xp0;
    const int t_abs = cc * chunk + tt;

    short8 bfr[4][4];  // ct = wave*4+i, kt 0..3
    #pragma unroll
    for (int i = 0; i < 4; ++i)
      #pragma unroll
      for (int kt = 0; kt < 4; ++kt)
        bfr[i][kt] = *(const short8*)(w_in_p + (((kt * 32 + wave * 4 + i) * 64 + lane) << 3));
    float brv[4];
    #pragma unroll
    for (int i = 0; i < 4; ++i) brv[i] = b_rec[(wave * 4 + i) * 16 + l15];

    for (int it = 0; it < 16; ++it) {
      const float* arow = inputs + ((size_t)t_abs * BATCH + it * 16 + l15) * INSZ + q * 8;
      short8 afr[4];
      #pragma unroll
      for (int kt = 0; kt < 4; ++kt) {
        short8 s;
        #pragma unroll
        for (int j = 0; j < 4; ++j) {
          unsigned u = cvt_pk_bf16(arow[kt * 32 + 2 * j], arow[kt * 32 + 2 * j + 1]);
          s[2 * j] = (short)(u & 0xffffu);
          s[2 * j + 1] = (short)(u >> 16);
        }
        afr[kt] = s;
      }
      floatx4 acc[4];
      #pragma unroll
      for (int i = 0; i < 4; ++i) acc[i] = (floatx4){0.f, 0.f, 0.f, 0.f};
      #pragma unroll
      for (int kt = 0; kt < 4; ++kt)
        #pragma unroll
        for (int i = 0; i < 4; ++i)
          acc[i] = MFMA16(afr[kt], bfr[i][kt], acc[i]);
      // store (acc + b_rec) as bf16 in fragment-linear layout: 8B/thread/ct
      #pragma unroll
      for (int i = 0; i < 4; ++i) {
        unsigned u01 = cvt_pk_bf16(acc[i][0] + brv[i], acc[i][1] + brv[i]);
        unsigned u23 = cvt_pk_bf16(acc[i][2] + brv[i], acc[i][3] + brv[i]);
        uint2 u; u.x = u01; u.y = u23;
        *(uint2*)(xpw + ((((size_t)tt * 16 + it) * 32 + wave * 4 + i) * 64 + lane) * 4) = u;
      }
    }

  } else {
    // ================= out role: one timestep of chunk c-1 ==================
    const int tt = bid - sb - nx;
    const int cc = c - 1;
    const short* hsr = (cc & 1) ? hs1 : hs0;
    short* al = (short*)smem + wave * (16 * 520);  // wave-private padded tile

    short8 bfr[16][2];
    #pragma unroll
    for (int kt = 0; kt < 16; ++kt)
      #pragma unroll
      for (int ot = 0; ot < 2; ++ot)
        bfr[kt][ot] = *(const short8*)(w_out_p + (((kt * 2 + ot) * 64 + lane) << 3));
    float bov[2] = { b_out[l15], b_out[16 + l15] };

    #pragma unroll
    for (int itm = 0; itm < 2; ++itm) {
      int mt = wave * 2 + itm;  // 16-row group within the timestep
      const short* src = hsr + ((size_t)tt * BATCH + mt * 16) * HID;
      #pragma unroll
      for (int r = 0; r < 16; ++r)
        *(short8*)(al + r * 520 + lane * 8) = *(const short8*)(src + r * 512 + lane * 8);
      // wave-private tile: in-wave DS ordering suffices, no barrier

      floatx4 acc2[2];
      acc2[0] = (floatx4){0.f, 0.f, 0.f, 0.f};
      acc2[1] = (floatx4){0.f, 0.f, 0.f, 0.f};
      #pragma unroll
      for (int kt = 0; kt < 16; ++kt) {
        short8 afr = *(const short8*)(al + l15 * 520 + kt * 32 + q * 8);
        acc2[0] = MFMA16(afr, bfr[kt][0], acc2[0]);
        acc2[1] = MFMA16(afr, bfr[kt][1], acc2[1]);
      }
      float* outp = out + ((size_t)(cc * chunk + tt) * BATCH + mt * 16) * OUTSZ;
      #pragma unroll
      for (int ot = 0; ot < 2; ++ot)
        #pragma unroll
        for (int r = 0; r < 4; ++r)
          outp[(size_t)(q * 4 + r) * OUTSZ + ot * 16 + l15] = acc2[ot][r] + bov[ot];
    }
  }
}

// ---------------------------------------------------------------------------
extern "C" void kernel_launch(void* const* d_in, const int* in_sizes, int n_in,
                              void* d_out, int out_size, void* d_ws, size_t ws_size,
                              hipStream_t stream) {
  const float* inputs = (const float*)d_in[0];  // [1024,256,128]
  const float* W_rec  = (const float*)d_in[1];  // [512,512]
  const float* W_in   = (const float*)d_in[2];  // [128,512]
  const float* b_rec  = (const float*)d_in[3];  // [512]
  const float* W_out  = (const float*)d_in[4];  // [512,32]
  const float* b_out  = (const float*)d_in[5];  // [32]
  float* out = (float*)d_out;                   // [1024,256,32]

  char* ws = (char*)d_ws;
  // fixed region (< 2 MB): packed weights + fp32 h carry
  short* w_rec_p = (short*)(ws);                       // 512 KB
  short* w_in_p  = (short*)(ws + 524288);              // 128 KB
  short* w_out_p = (short*)(ws + 655360);              //  32 KB
  float* h_carry = (float*)(ws + 688128);              // 512 KB
  const size_t fixed_end = 2u << 20;                   // 2 MB

  // double-buffered xp + hs: 4 buffers of chunk*256KB each -> 1 MB per step
  const size_t per_step = (size_t)BATCH * HID * 2 * 4;
  int chunk = T_STEPS;
  while (chunk > 1 && fixed_end + (size_t)chunk * per_step > ws_size) chunk >>= 1;
  if (fixed_end + (size_t)chunk * per_step > ws_size) return;  // ws too small
  const int nchunks = T_STEPS / chunk;

  const size_t buf = (size_t)chunk * BATCH * HID * 2;  // bytes per buffer
  short* xp0 = (short*)(ws + fixed_end);
  short* xp1 = (short*)(ws + fixed_end + buf);
  short* hs0 = (short*)(ws + fixed_end + 2 * buf);
  short* hs1 = (short*)(ws + fixed_end + 3 * buf);

  pack_kernel<<<1024, 256, 0, stream>>>(W_rec, W_in, W_out, w_rec_p, w_in_p, w_out_p);

  for (int c = -1; c <= nchunks; ++c) {
    int sb = (c >= 0 && c < nchunks) ? 16 : 0;
    int nx = (c + 1 >= 0 && c + 1 < nchunks) ? chunk : 0;
    int no = (c - 1 >= 0 && c - 1 < nchunks) ? chunk : 0;
    int grid = sb + nx + no;
    if (!grid) continue;
    fused_kernel<<<grid, 512, 0, stream>>>(inputs, w_rec_p, w_in_p, w_out_p,
        b_rec, b_out, xp0, xp1, hs0, hs1, h_carry, out, c, chunk, nchunks);
  }
}

// Round 3
// 4729.642 us; speedup vs baseline: 1.0133x; 1.0085x over previous
//
#include <hip/hip_runtime.h>

typedef __attribute__((ext_vector_type(8))) short short8;
typedef __attribute__((ext_vector_type(4))) float floatx4;

#define T_STEPS 1024
#define BATCH   256
#define INSZ    128
#define HID     512
#define OUTSZ   32

#define MFMA16(a,b,c) __builtin_amdgcn_mfma_f32_16x16x32_bf16((a),(b),(c),0,0,0)

// bf16 helpers (RNE)
static __device__ __forceinline__ short f2bf(float f) {
  unsigned int u = __float_as_uint(f);
  u += 0x7fffu + ((u >> 16) & 1u);
  return (short)(u >> 16);
}
static __device__ __forceinline__ float bf2f(short s) {
  return __uint_as_float(((unsigned int)(unsigned short)s) << 16);
}
// packed f32->bf16 (RNE), 1 inst for 2 values
static __device__ __forceinline__ unsigned cvt_pk_bf16(float lo, float hi) {
  unsigned r;
  asm("v_cvt_pk_bf16_f32 %0, %1, %2" : "=v"(r) : "v"(lo), "v"(hi));
  return r;
}

// ---------------------------------------------------------------------------
// Pack weights into MFMA B-fragment-linear bf16 layouts.
// B-frag for 16x16x32: lane = ((k%32)/8)*16 + (n%16), elem j = k%8.
// frag id = kt*NT + nt ; pos = (frag*64 + lane)*8 + j
// ---------------------------------------------------------------------------
__global__ __launch_bounds__(256) void pack_kernel(
    const float* __restrict__ W_rec, const float* __restrict__ W_in,
    const float* __restrict__ W_out,
    short* __restrict__ w_rec_p, short* __restrict__ w_in_p,
    short* __restrict__ w_out_p) {
  int i = blockIdx.x * 256 + threadIdx.x;  // 0..262143
  {
    // W_rec[n][k] used as B[k][n]  (h @ W_rec^T)
    int n = i >> 9, k = i & 511;
    int pos = ((((k >> 5) * 32 + (n >> 4)) * 64 + ((k >> 3) & 3) * 16 + (n & 15)) << 3) + (k & 7);
    w_rec_p[pos] = f2bf(W_rec[i]);
  }
  if (i < INSZ * HID) {
    int k = i >> 9, n = i & 511;  // W_in[k][n] used as B[k][n]
    int pos = ((((k >> 5) * 32 + (n >> 4)) * 64 + ((k >> 3) & 3) * 16 + (n & 15)) << 3) + (k & 7);
    w_in_p[pos] = f2bf(W_in[i]);
  }
  if (i < HID * OUTSZ) {
    int k = i >> 5, o = i & 31;   // W_out[k][o] used as B[k][o], NT=2
    int pos = ((((k >> 5) * 2 + (o >> 4)) * 64 + ((k >> 3) & 3) * 16 + (o & 15)) << 3) + (k & 7);
    w_out_p[pos] = f2bf(W_out[i]);
  }
}

// ---------------------------------------------------------------------------
// Fused kernel, launched once per chunk phase c in [-1, nchunks]:
//   blocks [0,16)            : scan of chunk c          (if 0 <= c < nchunks)
//   blocks [16, 16+chunk)    : xproj of chunk c+1       (if c+1 < nchunks)
//   remaining chunk blocks   : out GEMM of chunk c-1    (if c-1 >= 0)
// xp / hs are double-buffered so all roles are independent within a launch.
//
// Occupancy: 160KB LDS forces 1 workgroup/CU = 8 waves = 2 waves/EU.
// amdgpu_waves_per_eu(2,2) makes the compiler TARGET exactly that (cap and
// goal both 256 VGPR), so the 192-reg wreg tile is kept resident instead of
// being rematerialized (re-loaded from L2) every timestep -- previous rounds
// showed VGPR_Count=128 with per-step wreg re-fetch as the scan bottleneck.
// The empty asm pins below make the loaded fragments non-rematerializable.
// ---------------------------------------------------------------------------
__global__
__attribute__((amdgpu_flat_work_group_size(512, 512)))
__attribute__((amdgpu_waves_per_eu(2, 2)))
void fused_kernel(
    const float* __restrict__ inputs,
    const short* __restrict__ w_rec_p, const short* __restrict__ w_in_p,
    const short* __restrict__ w_out_p,
    const float* __restrict__ b_rec, const float* __restrict__ b_out,
    short* __restrict__ xp0, short* __restrict__ xp1,
    short* __restrict__ hs0, short* __restrict__ hs1,
    float* __restrict__ h_carry, float* __restrict__ out,
    int c, int chunk, int nchunks) {
  __shared__ __align__(16) char smem[163840];  // union: scan 160K / out 8*16640
  const int tid  = threadIdx.x;
  const int wave = tid >> 6, lane = tid & 63;
  const int l15  = lane & 15, q = lane >> 4;

  const int sb = (c >= 0 && c < nchunks) ? 16 : 0;
  const int nx = (c + 1 < nchunks) ? chunk : 0;
  const int bid = blockIdx.x;

  if (bid < sb) {
    // ================= scan role: chunk c, 16 batch rows per block ==========
    short* w_lds = (short*)smem;               // 128 KB: W_rec ktiles 12..15
    short* hbuf  = (short*)(smem + 131072);    // 2 x 16KB double-buffered h
    const short* xp = (c & 1) ? xp1 : xp0;
    short* hs = (c & 1) ? hs1 : hs0;
    const int slab = bid * 16;
    const int first = (c == 0);

    // resident weight fragments, ktiles 0..11 (wave owns cols [wave*64,+64))
    short8 wreg[12][4];
    #pragma unroll
    for (int kt = 0; kt < 12; ++kt)
      #pragma unroll
      for (int nt = 0; nt < 4; ++nt)
        wreg[kt][nt] = *(const short8*)(w_rec_p + (((kt * 32 + wave * 4 + nt) * 64 + lane) << 3));

    // pin: asm-defined values cannot be rematerialized from their loads
    #pragma unroll
    for (int kt = 0; kt < 12; ++kt)
      #pragma unroll
      for (int nt = 0; nt < 4; ++nt)
        asm volatile("" : "+v"(wreg[kt][nt]));

    // ktiles 12..15 -> LDS (frag-linear region contiguous in w_rec_p)
    for (int e = tid * 8; e < 4 * 32 * 512; e += 512 * 8)
      *(short8*)(w_lds + e) = *(const short8*)(w_rec_p + 12 * 32 * 512 + e);

    // carried state -> fp32 regs + swizzled bf16 LDS (buffer 0)
    float hold[4][4];
    #pragma unroll
    for (int nt = 0; nt < 4; ++nt) {
      int col = wave * 64 + nt * 16 + l15;
      int ck = col >> 3, cl = col & 7;
      #pragma unroll
      for (int r = 0; r < 4; ++r) {
        int row = q * 4 + r;
        float v = 0.f;
        if (!first) v = h_carry[(size_t)(slab + row) * HID + col];
        hold[nt][r] = v;
        hbuf[row * 512 + ((ck ^ row) << 3) + cl] = f2bf(v);
      }
    }

    // prefetch xp for t=0 into registers (4 x 8B, coalesced)
    uint2 xv[4];
    #pragma unroll
    for (int nt = 0; nt < 4; ++nt)
      xv[nt] = *(const uint2*)(xp + ((((size_t)0 * 16 + bid) * 32 + wave * 4 + nt) * 64 + lane) * 4);

    const float alpha = (float)(0.1 / 100.0);
    const float onem  = (float)(1.0 - 0.1 / 100.0);

    __syncthreads();

    int p = 0;
    for (int t = 0; t < chunk; ++t) {
      const short* hb = hbuf + p * (16 * 512);        // state h_{t}
      short* hnb = hbuf + (p ^ 1) * (16 * 512);       // will hold h_{t+1}

      // acc init = xp[t] (C-in of MFMA) -- replaces LDS xp staging + add
      floatx4 acc[4];
      #pragma unroll
      for (int nt = 0; nt < 4; ++nt) {
        acc[nt][0] = bf2f((short)(xv[nt].x & 0xffffu));
        acc[nt][1] = bf2f((short)(xv[nt].x >> 16));
        acc[nt][2] = bf2f((short)(xv[nt].y & 0xffffu));
        acc[nt][3] = bf2f((short)(xv[nt].y >> 16));
      }
      // prefetch xp[t+1]; retires long before the barrier
      if (t + 1 < chunk) {
        #pragma unroll
        for (int nt = 0; nt < 4; ++nt)
          xv[nt] = *(const uint2*)(xp + ((((size_t)(t + 1) * 16 + bid) * 32 + wave * 4 + nt) * 64 + lane) * 4);
      }

      // store hs[t-1] from stable buffer hb (reads-only overlap with MFMA)
      if (t > 0) {
        int e = tid * 16;
        int row = e >> 9, c0 = (e & 511) >> 3;
        short8 v0 = *(const short8*)(hb + row * 512 + (((c0    ) ^ row) << 3));
        short8 v1 = *(const short8*)(hb + row * 512 + (((c0 + 1) ^ row) << 3));
        short* dst = hs + ((size_t)(t - 1) * BATCH + slab) * HID + e;
        *(short8*)(dst) = v0;
        *(short8*)(dst + 8) = v1;
      }

      // MFMA: h_t @ W_rec^T, ktiles 0..11 from regs, 12..15 from LDS
      #pragma unroll
      for (int kt = 0; kt < 12; ++kt) {
        short8 afr = *(const short8*)(hb + l15 * 512 + (((kt * 4 + q) ^ l15) << 3));
        #pragma unroll
        for (int nt = 0; nt < 4; ++nt)
          acc[nt] = MFMA16(afr, wreg[kt][nt], acc[nt]);
      }
      #pragma unroll
      for (int kt = 12; kt < 16; ++kt) {
        short8 afr = *(const short8*)(hb + l15 * 512 + (((kt * 4 + q) ^ l15) << 3));
        #pragma unroll
        for (int nt = 0; nt < 4; ++nt) {
          short8 bfr = *(const short8*)(w_lds + (((kt - 12) * 32 + wave * 4 + nt) << 9) + lane * 8);
          acc[nt] = MFMA16(afr, bfr, acc[nt]);
        }
      }

      // epilogue: CTRNN update in fp32 regs, write bf16 h_{t+1} to other buf
      #pragma unroll
      for (int nt = 0; nt < 4; ++nt) {
        int col = wave * 64 + nt * 16 + l15;
        int ck = col >> 3, cl = col & 7;
        float h0 = onem * hold[nt][0] + alpha * fmaxf(acc[nt][0], 0.f);
        float h1 = onem * hold[nt][1] + alpha * fmaxf(acc[nt][1], 0.f);
        float h2 = onem * hold[nt][2] + alpha * fmaxf(acc[nt][2], 0.f);
        float h3 = onem * hold[nt][3] + alpha * fmaxf(acc[nt][3], 0.f);
        hold[nt][0] = h0; hold[nt][1] = h1; hold[nt][2] = h2; hold[nt][3] = h3;
        unsigned u01 = cvt_pk_bf16(h0, h1);
        unsigned u23 = cvt_pk_bf16(h2, h3);
        int r0 = q * 4;
        hnb[(r0 + 0) * 512 + ((ck ^ (r0 + 0)) << 3) + cl] = (short)(u01 & 0xffffu);
        hnb[(r0 + 1) * 512 + ((ck ^ (r0 + 1)) << 3) + cl] = (short)(u01 >> 16);
        hnb[(r0 + 2) * 512 + ((ck ^ (r0 + 2)) << 3) + cl] = (short)(u23 & 0xffffu);
        hnb[(r0 + 3) * 512 + ((ck ^ (r0 + 3)) << 3) + cl] = (short)(u23 >> 16);
      }
      __syncthreads();  // single barrier per step (WAR safe: write buf != read buf)
      p ^= 1;
    }

    // tail: hs[chunk-1] + fp32 carry
    {
      const short* hb = hbuf + p * (16 * 512);
      int e = tid * 16;
      int row = e >> 9, c0 = (e & 511) >> 3;
      short8 v0 = *(const short8*)(hb + row * 512 + (((c0    ) ^ row) << 3));
      short8 v1 = *(const short8*)(hb + row * 512 + (((c0 + 1) ^ row) << 3));
      short* dst = hs + ((size_t)(chunk - 1) * BATCH + slab) * HID + e;
      *(short8*)(dst) = v0;
      *(short8*)(dst + 8) = v1;
    }
    #pragma unroll
    for (int nt = 0; nt < 4; ++nt) {
      int col = wave * 64 + nt * 16 + l15;
      #pragma unroll
      for (int r = 0; r < 4; ++r)
        h_carry[(size_t)(slab + q * 4 + r) * HID + col] = hold[nt][r];
    }

  } else if (bid - sb < nx) {
    // ================= xproj role: one timestep of chunk c+1 ================
    const int tt = bid - sb;
    const int cc = c + 1;
    short* xpw = (cc & 1) ? xp1 : xp0;
    const int t_abs = cc * chunk + tt;

    short8 bfr[4][4];  // ct = wave*4+i, kt 0..3
    #pragma unroll
    for (int i = 0; i < 4; ++i)
      #pragma unroll
      for (int kt = 0; kt < 4; ++kt)
        bfr[i][kt] = *(const short8*)(w_in_p + (((kt * 32 + wave * 4 + i) * 64 + lane) << 3));
    float brv[4];
    #pragma unroll
    for (int i = 0; i < 4; ++i) brv[i] = b_rec[(wave * 4 + i) * 16 + l15];

    for (int it = 0; it < 16; ++it) {
      const float* arow = inputs + ((size_t)t_abs * BATCH + it * 16 + l15) * INSZ + q * 8;
      short8 afr[4];
      #pragma unroll
      for (int kt = 0; kt < 4; ++kt) {
        short8 s;
        #pragma unroll
        for (int j = 0; j < 4; ++j) {
          unsigned u = cvt_pk_bf16(arow[kt * 32 + 2 * j], arow[kt * 32 + 2 * j + 1]);
          s[2 * j] = (short)(u & 0xffffu);
          s[2 * j + 1] = (short)(u >> 16);
        }
        afr[kt] = s;
      }
      floatx4 acc[4];
      #pragma unroll
      for (int i = 0; i < 4; ++i) acc[i] = (floatx4){0.f, 0.f, 0.f, 0.f};
      #pragma unroll
      for (int kt = 0; kt < 4; ++kt)
        #pragma unroll
        for (int i = 0; i < 4; ++i)
          acc[i] = MFMA16(afr[kt], bfr[i][kt], acc[i]);
      // store (acc + b_rec) as bf16 in fragment-linear layout: 8B/thread/ct
      #pragma unroll
      for (int i = 0; i < 4; ++i) {
        unsigned u01 = cvt_pk_bf16(acc[i][0] + brv[i], acc[i][1] + brv[i]);
        unsigned u23 = cvt_pk_bf16(acc[i][2] + brv[i], acc[i][3] + brv[i]);
        uint2 u; u.x = u01; u.y = u23;
        *(uint2*)(xpw + ((((size_t)tt * 16 + it) * 32 + wave * 4 + i) * 64 + lane) * 4) = u;
      }
    }

  } else {
    // ================= out role: one timestep of chunk c-1 ==================
    const int tt = bid - sb - nx;
    const int cc = c - 1;
    const short* hsr = (cc & 1) ? hs1 : hs0;
    short* al = (short*)smem + wave * (16 * 520);  // wave-private padded tile

    short8 bfr[16][2];
    #pragma unroll
    for (int kt = 0; kt < 16; ++kt)
      #pragma unroll
      for (int ot = 0; ot < 2; ++ot)
        bfr[kt][ot] = *(const short8*)(w_out_p + (((kt * 2 + ot) * 64 + lane) << 3));
    float bov[2] = { b_out[l15], b_out[16 + l15] };

    #pragma unroll
    for (int itm = 0; itm < 2; ++itm) {
      int mt = wave * 2 + itm;  // 16-row group within the timestep
      const short* src = hsr + ((size_t)tt * BATCH + mt * 16) * HID;
      #pragma unroll
      for (int r = 0; r < 16; ++r)
        *(short8*)(al + r * 520 + lane * 8) = *(const short8*)(src + r * 512 + lane * 8);
      // wave-private tile: in-wave DS ordering suffices, no barrier

      floatx4 acc2[2];
      acc2[0] = (floatx4){0.f, 0.f, 0.f, 0.f};
      acc2[1] = (floatx4){0.f, 0.f, 0.f, 0.f};
      #pragma unroll
      for (int kt = 0; kt < 16; ++kt) {
        short8 afr = *(const short8*)(al + l15 * 520 + kt * 32 + q * 8);
        acc2[0] = MFMA16(afr, bfr[kt][0], acc2[0]);
        acc2[1] = MFMA16(afr, bfr[kt][1], acc2[1]);
      }
      float* outp = out + ((size_t)(cc * chunk + tt) * BATCH + mt * 16) * OUTSZ;
      #pragma unroll
      for (int ot = 0; ot < 2; ++ot)
        #pragma unroll
        for (int r = 0; r < 4; ++r)
          outp[(size_t)(q * 4 + r) * OUTSZ + ot * 16 + l15] = acc2[ot][r] + bov[ot];
    }
  }
}

// ---------------------------------------------------------------------------
extern "C" void kernel_launch(void* const* d_in, const int* in_sizes, int n_in,
                              void* d_out, int out_size, void* d_ws, size_t ws_size,
                              hipStream_t stream) {
  const float* inputs = (const float*)d_in[0];  // [1024,256,128]
  const float* W_rec  = (const float*)d_in[1];  // [512,512]
  const float* W_in   = (const float*)d_in[2];  // [128,512]
  const float* b_rec  = (const float*)d_in[3];  // [512]
  const float* W_out  = (const float*)d_in[4];  // [512,32]
  const float* b_out  = (const float*)d_in[5];  // [32]
  float* out = (float*)d_out;                   // [1024,256,32]

  char* ws = (char*)d_ws;
  // fixed region (< 2 MB): packed weights + fp32 h carry
  short* w_rec_p = (short*)(ws);                       // 512 KB
  short* w_in_p  = (short*)(ws + 524288);              // 128 KB
  short* w_out_p = (short*)(ws + 655360);              //  32 KB
  float* h_carry = (float*)(ws + 688128);              // 512 KB
  const size_t fixed_end = 2u << 20;                   // 2 MB

  // double-buffered xp + hs: 4 buffers of chunk*256KB each -> 1 MB per step
  const size_t per_step = (size_t)BATCH * HID * 2 * 4;
  int chunk = T_STEPS;
  while (chunk > 1 && fixed_end + (size_t)chunk * per_step > ws_size) chunk >>= 1;
  if (fixed_end + (size_t)chunk * per_step > ws_size) return;  // ws too small
  const int nchunks = T_STEPS / chunk;

  const size_t buf = (size_t)chunk * BATCH * HID * 2;  // bytes per buffer
  short* xp0 = (short*)(ws + fixed_end);
  short* xp1 = (short*)(ws + fixed_end + buf);
  short* hs0 = (short*)(ws + fixed_end + 2 * buf);
  short* hs1 = (short*)(ws + fixed_end + 3 * buf);

  pack_kernel<<<1024, 256, 0, stream>>>(W_rec, W_in, W_out, w_rec_p, w_in_p, w_out_p);

  for (int c = -1; c <= nchunks; ++c) {
    int sb = (c >= 0 && c < nchunks) ? 16 : 0;
    int nx = (c + 1 >= 0 && c + 1 < nchunks) ? chunk : 0;
    int no = (c - 1 >= 0 && c - 1 < nchunks) ? chunk : 0;
    int grid = sb + nx + no;
    if (!grid) continue;
    fused_kernel<<<grid, 512, 0, stream>>>(inputs, w_rec_p, w_in_p, w_out_p,
        b_rec, b_out, xp0, xp1, hs0, hs1, h_carry, out, c, chunk, nchunks);
  }
}